// Round 1
// baseline (223.833 us; speedup 1.0000x reference)
//
#include <hip/hip_runtime.h>

typedef _Float16 half_t;
typedef _Float16 v8h __attribute__((ext_vector_type(8)));
typedef float v4f __attribute__((ext_vector_type(4)));

#define XTP 40   // xt LDS row pitch (halves): 32 data + 8 pad (keeps 16B align)
#define HP  72   // h  LDS row pitch (halves): 64 data + 8 pad

// ============ prep: x (B,32,16) f32 -> xt (B,16,32) f16 (transpose f<->e) ============
__global__ __launch_bounds__(256) void prep_x(const float* __restrict__ x, half_t* __restrict__ xt) {
  __shared__ half_t t[8 * 512];
  const int tid = threadIdx.x;
  const size_t b0 = (size_t)blockIdx.x * 8;
#pragma unroll
  for (int i = 0; i < 4; ++i) {
    int idx = (i * 256 + tid) * 4;           // element index within 8 batch rows
    float4 v = *(const float4*)(x + b0 * 512 + idx);
    int e = idx & 15, f = (idx >> 4) & 31, b = idx >> 9;
    half_t* d = t + b * 512 + f;             // t layout [b][e*32+f]
    d[(e + 0) * 32] = (half_t)v.x;
    d[(e + 1) * 32] = (half_t)v.y;
    d[(e + 2) * 32] = (half_t)v.z;
    d[(e + 3) * 32] = (half_t)v.w;
  }
  __syncthreads();
#pragma unroll
  for (int i = 0; i < 2; ++i) {
    int c = i * 256 + tid;
    *(uint4*)(xt + b0 * 512 + c * 8) = *(const uint4*)(t + c * 8);
  }
}

// ===== prep: W (128,K) f32 -> f16 chunked [K/8][128][8]: chunk (k>>3)*128+o = W[o][k..k+8) =====
__global__ __launch_bounds__(256) void prep_w(const float* __restrict__ src, half_t* __restrict__ dst,
                                              int ktot, int nchunk) {
  int i = blockIdx.x * 256 + threadIdx.x;
  if (i >= nchunk) return;
  int o = i & 127, k8 = i >> 7;
  const float* s = src + (size_t)o * ktot + k8 * 8;
  float4 f0 = *(const float4*)s;
  float4 f1 = *(const float4*)(s + 4);
  union { half_t h[8]; uint4 u; } pk;
  pk.h[0] = (half_t)f0.x; pk.h[1] = (half_t)f0.y; pk.h[2] = (half_t)f0.z; pk.h[3] = (half_t)f0.w;
  pk.h[4] = (half_t)f1.x; pk.h[5] = (half_t)f1.y; pk.h[6] = (half_t)f1.z; pk.h[7] = (half_t)f1.w;
  *(uint4*)(dst + (size_t)i * 8) = pk.u;
}

// ============ one CIN layer: Y = relu(W @ Z + b), Z built on the fly ============
// Block: 256 thr, tile M=128(o) x N=128(= 8 batch * 16 e). Wave tile 64x64, mfma 16x16x32 f16.
template <int G, int KTOT, int KEEP, int OUT_BASE, bool H_OUT, bool H_IS_X>
__global__ __launch_bounds__(256) void cin_layer(const half_t* __restrict__ xt,
                                                 const half_t* __restrict__ hin,
                                                 const half_t* __restrict__ wgt,
                                                 const float* __restrict__ bias,
                                                 half_t* __restrict__ hout,
                                                 float* __restrict__ out) {
  constexpr int NS = KTOT / 32;
  constexpr int LOG2G = (G == 32) ? 5 : 6;
  constexpr int HSZ = H_IS_X ? 8 : 8 * 16 * HP;
  __shared__ __align__(16) half_t xt_lds[8 * 16 * XTP];
  __shared__ __align__(16) half_t h_lds_arr[HSZ];
  __shared__ __align__(16) half_t w_lds[2 * 4096];
  __shared__ float bias_lds[128];

  const int tid = threadIdx.x;
  const int lane = tid & 63;
  const int wv = tid >> 6;
  const size_t b0 = (size_t)blockIdx.x * 8;

  // ---- stage xt: 128 rows (b,e) x 32 halves ----
  {
    const int r = tid >> 1, c = (tid & 1) * 16;
    const half_t* src = xt + b0 * 512 + r * 32 + c;
    uint4 q0 = *(const uint4*)(src);
    uint4 q1 = *(const uint4*)(src + 8);
    *(uint4*)(xt_lds + r * XTP + c) = q0;
    *(uint4*)(xt_lds + r * XTP + c + 8) = q1;
  }
  // ---- stage h: 128 rows (b,e) x 64 halves ----
  if (!H_IS_X) {
    const int r = tid >> 1, c = (tid & 1) * 32;
    const half_t* src = hin + b0 * 1024 + r * 64 + c;
    uint4 q0 = *(const uint4*)(src);
    uint4 q1 = *(const uint4*)(src + 8);
    uint4 q2 = *(const uint4*)(src + 16);
    uint4 q3 = *(const uint4*)(src + 24);
    half_t* dst = h_lds_arr + r * HP + c;
    *(uint4*)(dst) = q0;
    *(uint4*)(dst + 8) = q1;
    *(uint4*)(dst + 16) = q2;
    *(uint4*)(dst + 24) = q3;
  }
  if (tid < 128) bias_lds[tid] = bias[tid];

  // ---- W register prefetch (chunked layout -> coalesced) ----
  const half_t* wg = wgt + (size_t)tid * 8;
  uint4 wr0 = *(const uint4*)(wg);
  uint4 wr1 = *(const uint4*)(wg + 2048);

  const int wm = (wv & 1) * 64;        // o offset of wave
  const int wb_ofs = (wv >> 1) * 4;    // batch offset of wave within block
  const int col = lane & 15;           // = e, and A/B/C intra-tile index
  const int kq = lane >> 4;            // k-quad

  const half_t* hbase = H_IS_X ? xt_lds : h_lds_arr;
  constexpr int HPITCH = H_IS_X ? XTP : HP;

  v4f acc[4][4] = {};

  for (int s = 0; s < NS; ++s) {
    half_t* wb = w_lds + (s & 1) * 4096;
    *(uint4*)(wb + tid * 8) = wr0;
    *(uint4*)(wb + tid * 8 + 2048) = wr1;
    __syncthreads();  // one barrier per K-step (store->compute); buffers alternate
    if (s + 1 < NS) {
      wr0 = *(const uint4*)(wg + (s + 1) * 4096);         // in flight during compute
      wr1 = *(const uint4*)(wg + (s + 1) * 4096 + 2048);
    }
    const int k_abs = s * 32 + kq * 8;
    const int f = k_abs >> LOG2G;      // wave-uniform per step
    const int g0 = k_abs & (G - 1);
    v8h a[4], bfr[4];
#pragma unroll
    for (int mi = 0; mi < 4; ++mi)
      a[mi] = *(const v8h*)(wb + (kq * 128 + wm + mi * 16 + col) * 8);
#pragma unroll
    for (int ni = 0; ni < 4; ++ni) {
      const int row = (wb_ofs + ni) * 16 + col;           // (b_local, e) row
      v8h hv = *(const v8h*)(hbase + row * HPITCH + g0);
      half_t xs = xt_lds[row * XTP + f];
      bfr[ni] = hv * xs;                                  // Z fragment: x0[f,e]*h[g,e]
    }
#pragma unroll
    for (int mi = 0; mi < 4; ++mi)
#pragma unroll
      for (int ni = 0; ni < 4; ++ni)
        acc[mi][ni] = __builtin_amdgcn_mfma_f32_16x16x32_f16(a[mi], bfr[ni], acc[mi][ni], 0, 0, 0);
  }

  // ---- epilogue: bias + relu; rows>=64 -> h_next; rows<KEEP -> sum_e -> out ----
#pragma unroll
  for (int mi = 0; mi < 4; ++mi) {
    const int o_base = wm + mi * 16 + kq * 4;  // C row base for this lane (rows o_base..o_base+3)
#pragma unroll
    for (int ni = 0; ni < 4; ++ni) {
      const int bb = wb_ofs + ni;
      float v[4];
#pragma unroll
      for (int r = 0; r < 4; ++r)
        v[r] = fmaxf(acc[mi][ni][r] + bias_lds[o_base + r], 0.0f);
      if (H_OUT && o_base >= 64) {   // wave-uniform: only wm=64 waves
        union { half_t h[4]; uint2 u; } pk;
#pragma unroll
        for (int r = 0; r < 4; ++r) pk.h[r] = (half_t)v[r];
        *(uint2*)(hout + ((b0 + bb) * 16 + col) * 64 + (o_base - 64)) = pk.u;
      }
      if (o_base < KEEP) {           // wave-uniform
#pragma unroll
        for (int r = 0; r < 4; ++r) {
          float sv = v[r];
          sv += __shfl_xor(sv, 1);
          sv += __shfl_xor(sv, 2);
          sv += __shfl_xor(sv, 4);
          sv += __shfl_xor(sv, 8);   // sum over e (16-lane group)
          if (col == 0) out[(b0 + bb) * 256 + OUT_BASE + o_base + r] = sv;
        }
      }
    }
  }
}

extern "C" void kernel_launch(void* const* d_in, const int* in_sizes, int n_in,
                              void* d_out, int out_size, void* d_ws, size_t ws_size,
                              hipStream_t stream) {
  const float* x  = (const float*)d_in[0];
  const float* W0 = (const float*)d_in[1];
  const float* b0 = (const float*)d_in[2];
  const float* W1 = (const float*)d_in[3];
  const float* b1 = (const float*)d_in[4];
  const float* W2 = (const float*)d_in[5];
  const float* b2 = (const float*)d_in[6];
  float* out = (float*)d_out;
  char* ws = (char*)d_ws;

  half_t* xt  = (half_t*)(ws);                          // 4 MB
  half_t* w0h = (half_t*)(ws + (4u << 20));             // 256 KB
  half_t* w1h = (half_t*)(ws + (4u << 20) + (256u << 10));   // 512 KB
  half_t* w2h = (half_t*)(ws + (4u << 20) + (768u << 10));   // 512 KB
  half_t* h1  = (half_t*)(ws + (4u << 20) + (1280u << 10));  // 8 MB
  half_t* h2  = (half_t*)(ws + (12u << 20) + (1280u << 10)); // 8 MB

  prep_x<<<512, 256, 0, stream>>>(x, xt);
  prep_w<<<64, 256, 0, stream>>>(W0, w0h, 1024, 16384);
  prep_w<<<128, 256, 0, stream>>>(W1, w1h, 2048, 32768);
  prep_w<<<128, 256, 0, stream>>>(W2, w2h, 2048, 32768);

  // layer 0: G=32 (h = x0), keep o<64 -> out ch [0,64), o>=64 -> h1
  cin_layer<32, 1024, 64, 0, true, true><<<512, 256, 0, stream>>>(xt, xt, w0h, b0, h1, out);
  // layer 1: G=64, keep o<64 -> out ch [64,128), o>=64 -> h2
  cin_layer<64, 2048, 64, 64, true, false><<<512, 256, 0, stream>>>(xt, h1, w1h, b1, h2, out);
  // layer 2: G=64, keep all 128 -> out ch [128,256)
  cin_layer<64, 2048, 128, 128, false, false><<<512, 256, 0, stream>>>(xt, h2, w2h, b2, nullptr, out);
}

// Round 2
// 201.284 us; speedup vs baseline: 1.1120x; 1.1120x over previous
//
#include <hip/hip_runtime.h>

typedef _Float16 half_t;
typedef _Float16 v8h __attribute__((ext_vector_type(8)));
typedef float v4f __attribute__((ext_vector_type(4)));

#define XTP 40   // xt LDS row pitch (halves): 32 data + 8 pad (16B-aligned rows)

// ============ prep: x (B,32,16) f32 -> xt (B,16,32) f16 (transpose f<->e) ============
__global__ __launch_bounds__(256) void prep_x(const float* __restrict__ x, half_t* __restrict__ xt) {
  __shared__ half_t t[8 * 512];
  const int tid = threadIdx.x;
  const size_t b0 = (size_t)blockIdx.x * 8;
#pragma unroll
  for (int i = 0; i < 4; ++i) {
    int idx = (i * 256 + tid) * 4;           // element index within 8 batch rows
    float4 v = *(const float4*)(x + b0 * 512 + idx);
    int e = idx & 15, f = (idx >> 4) & 31, b = idx >> 9;
    half_t* d = t + b * 512 + f;             // t layout [b][e*32+f]
    d[(e + 0) * 32] = (half_t)v.x;
    d[(e + 1) * 32] = (half_t)v.y;
    d[(e + 2) * 32] = (half_t)v.z;
    d[(e + 3) * 32] = (half_t)v.w;
  }
  __syncthreads();
#pragma unroll
  for (int i = 0; i < 2; ++i) {
    int c = i * 256 + tid;
    *(uint4*)(xt + b0 * 512 + c * 8) = *(const uint4*)(t + c * 8);
  }
}

// ===== prep: W (128,K) f32 -> f16 chunked [K/8][128][8]: chunk (k>>3)*128+o = W[o][k..k+8) =====
__global__ __launch_bounds__(256) void prep_w(const float* __restrict__ src, half_t* __restrict__ dst,
                                              int ktot, int nchunk) {
  int i = blockIdx.x * 256 + threadIdx.x;
  if (i >= nchunk) return;
  int o = i & 127, k8 = i >> 7;
  const float* s = src + (size_t)o * ktot + k8 * 8;
  float4 f0 = *(const float4*)s;
  float4 f1 = *(const float4*)(s + 4);
  union { half_t h[8]; uint4 u; } pk;
  pk.h[0] = (half_t)f0.x; pk.h[1] = (half_t)f0.y; pk.h[2] = (half_t)f0.z; pk.h[3] = (half_t)f0.w;
  pk.h[4] = (half_t)f1.x; pk.h[5] = (half_t)f1.y; pk.h[6] = (half_t)f1.z; pk.h[7] = (half_t)f1.w;
  *(uint4*)(dst + (size_t)i * 8) = pk.u;
}

// ============ one CIN layer: Y = relu(W @ Z + b), Z built on the fly ============
// Block: 256 thr, tile M=128(o) x N=128(= 8 batch * 16 e). Wave tile 64x64, mfma 16x16x32 f16.
// Per lane, kq=lane>>4 is fixed => h fragment needs only 2 v8h per batch elem (register-resident).
// W streamed global->reg (L2-resident, coalesced chunks), 1-step prefetch; NO barrier in K-loop.
template <int G, int KTOT, int KEEP, int OUT_BASE, bool H_OUT, bool H_IS_X>
__global__ __launch_bounds__(256, 2) void cin_layer(const half_t* __restrict__ xt,
                                                    const half_t* __restrict__ hin,
                                                    const half_t* __restrict__ wgt,
                                                    const float* __restrict__ bias,
                                                    half_t* __restrict__ hout,
                                                    float* __restrict__ out) {
  constexpr int NS = KTOT / 32;            // K-steps of 32
  constexpr int SPO = (G == 64) ? 16 : 8;  // steps per f-octet
  constexpr int NOCT = NS / SPO;           // 4 for both layer shapes
  constexpr int NSEL = (G == 64) ? 2 : 1;
  __shared__ __align__(16) half_t xt_lds[128 * XTP];
  __shared__ float bias_lds[128];

  const int tid = threadIdx.x;
  const int lane = tid & 63;
  const int wv = tid >> 6;
  const size_t b0 = (size_t)blockIdx.x * 8;

  // ---- stage xt: 128 rows (b,e) x 32 halves ----
  {
    const int r = tid >> 1, c = (tid & 1) * 16;
    const half_t* src = xt + b0 * 512 + r * 32 + c;
    uint4 q0 = *(const uint4*)(src);
    uint4 q1 = *(const uint4*)(src + 8);
    *(uint4*)(xt_lds + r * XTP + c) = q0;
    *(uint4*)(xt_lds + r * XTP + c + 8) = q1;
  }
  if (tid < 128) bias_lds[tid] = bias[tid];

  const int wm = (wv & 1) * 64;        // o offset of wave
  const int wb = (wv >> 1) * 4;        // batch offset of wave within block
  const int col = lane & 15;           // = e (A/B/C intra-tile index)
  const int kq = lane >> 4;            // k-quad (fixed per lane)

  int lrow[4];
#pragma unroll
  for (int ni = 0; ni < 4; ++ni) lrow[ni] = (wb + ni) * 16 + col;

  // ---- h fragments: register-resident for the whole K-loop ----
  v8h hreg[4][NSEL];
  if (!H_IS_X) {
#pragma unroll
    for (int ni = 0; ni < 4; ++ni) {
      const half_t* hp = hin + ((b0 + wb + ni) * 16 + col) * 64 + kq * 8;
      hreg[ni][0] = *(const v8h*)(hp);
      if (NSEL > 1) hreg[ni][NSEL - 1] = *(const v8h*)(hp + 32);
    }
  }
  __syncthreads();   // xt_lds ready (single barrier in the kernel)
  if (H_IS_X) {
#pragma unroll
    for (int ni = 0; ni < 4; ++ni)
      hreg[ni][0] = *(const v8h*)(xt_lds + lrow[ni] * XTP + kq * 8);
  }

  // ---- W stream: lane's chunk index (kq*128 + o), step stride 512 chunks ----
  const v8h* wp = (const v8h*)wgt + (kq * 128 + wm + col);
  v8h aw[2][4];
#pragma unroll
  for (int mi = 0; mi < 4; ++mi) aw[0][mi] = wp[mi * 16];

  v4f acc[4][4] = {};

  for (int oct = 0; oct < NOCT; ++oct) {
    v8h xv[4];
#pragma unroll
    for (int ni = 0; ni < 4; ++ni)
      xv[ni] = *(const v8h*)(xt_lds + lrow[ni] * XTP + oct * 8);
#pragma unroll
    for (int t = 0; t < SPO; ++t) {
      // prefetch next step's W fragments (last one runs 8KB past W; ws region follows -> safe, unused)
#pragma unroll
      for (int mi = 0; mi < 4; ++mi)
        aw[(t + 1) & 1][mi] = wp[(t + 1) * 512 + mi * 16];
      const int j = (G == 64) ? (t >> 1) : t;     // f index within octet (static)
      const int sel = (G == 64) ? (t & 1) : 0;    // g-range select (static)
      v8h bfr[4];
#pragma unroll
      for (int ni = 0; ni < 4; ++ni)
        bfr[ni] = hreg[ni][sel] * xv[ni][j];      // Z fragment: x0[f,e]*h[g,e]
#pragma unroll
      for (int mi = 0; mi < 4; ++mi) {
        v8h a = aw[t & 1][mi];
#pragma unroll
        for (int ni = 0; ni < 4; ++ni)
          acc[mi][ni] = __builtin_amdgcn_mfma_f32_16x16x32_f16(a, bfr[ni], acc[mi][ni], 0, 0, 0);
      }
    }
    wp += SPO * 512;
  }

  // ---- epilogue: bias + relu; rows>=64 -> h_next; rows<KEEP -> sum_e -> out ----
#pragma unroll
  for (int mi = 0; mi < 4; ++mi) {
    const int o_base = wm + mi * 16 + kq * 4;  // C rows o_base..o_base+3 for this lane
#pragma unroll
    for (int ni = 0; ni < 4; ++ni) {
      const int bb = wb + ni;
      float v[4];
#pragma unroll
      for (int r = 0; r < 4; ++r)
        v[r] = fmaxf(acc[mi][ni][r] + bias_lds[o_base + r], 0.0f);
      if (H_OUT && o_base >= 64) {   // wave-uniform: only wm=64 waves
        union { half_t h[4]; uint2 u; } pk;
#pragma unroll
        for (int r = 0; r < 4; ++r) pk.h[r] = (half_t)v[r];
        *(uint2*)(hout + ((b0 + bb) * 16 + col) * 64 + (o_base - 64)) = pk.u;
      }
      if (o_base < KEEP) {           // wave-uniform
#pragma unroll
        for (int r = 0; r < 4; ++r) {
          float sv = v[r];
          sv += __shfl_xor(sv, 1);
          sv += __shfl_xor(sv, 2);
          sv += __shfl_xor(sv, 4);
          sv += __shfl_xor(sv, 8);   // sum over e (16-lane group)
          if (col == 0) out[(b0 + bb) * 256 + OUT_BASE + o_base + r] = sv;
        }
      }
    }
  }
}

extern "C" void kernel_launch(void* const* d_in, const int* in_sizes, int n_in,
                              void* d_out, int out_size, void* d_ws, size_t ws_size,
                              hipStream_t stream) {
  const float* x  = (const float*)d_in[0];
  const float* W0 = (const float*)d_in[1];
  const float* b0 = (const float*)d_in[2];
  const float* W1 = (const float*)d_in[3];
  const float* b1 = (const float*)d_in[4];
  const float* W2 = (const float*)d_in[5];
  const float* b2 = (const float*)d_in[6];
  float* out = (float*)d_out;
  char* ws = (char*)d_ws;

  half_t* xt  = (half_t*)(ws);                          // 4 MB
  half_t* w0h = (half_t*)(ws + (4u << 20));             // 256 KB
  half_t* w1h = (half_t*)(ws + (4u << 20) + (256u << 10));   // 512 KB
  half_t* w2h = (half_t*)(ws + (4u << 20) + (768u << 10));   // 512 KB
  half_t* h1  = (half_t*)(ws + (4u << 20) + (1280u << 10));  // 8 MB
  half_t* h2  = (half_t*)(ws + (12u << 20) + (1280u << 10)); // 8 MB

  prep_x<<<512, 256, 0, stream>>>(x, xt);
  prep_w<<<64, 256, 0, stream>>>(W0, w0h, 1024, 16384);
  prep_w<<<128, 256, 0, stream>>>(W1, w1h, 2048, 32768);
  prep_w<<<128, 256, 0, stream>>>(W2, w2h, 2048, 32768);

  // layer 0: G=32 (h = x0), keep o<64 -> out ch [0,64), o>=64 -> h1
  cin_layer<32, 1024, 64, 0, true, true><<<512, 256, 0, stream>>>(xt, xt, w0h, b0, h1, out);
  // layer 1: G=64, keep o<64 -> out ch [64,128), o>=64 -> h2
  cin_layer<64, 2048, 64, 64, true, false><<<512, 256, 0, stream>>>(xt, h1, w1h, b1, h2, out);
  // layer 2: G=64, keep all 128 -> out ch [128,256)
  cin_layer<64, 2048, 128, 128, false, false><<<512, 256, 0, stream>>>(xt, h2, w2h, b2, nullptr, out);
}

// Round 3
// 187.894 us; speedup vs baseline: 1.1913x; 1.0713x over previous
//
#include <hip/hip_runtime.h>

typedef _Float16 half_t;
typedef _Float16 v8h __attribute__((ext_vector_type(8)));
typedef float v4f __attribute__((ext_vector_type(4)));

#define XTP 40   // xt LDS row pitch (halves): 32 data + 8 pad (16B-aligned rows)

typedef __attribute__((address_space(3))) unsigned int lds_u32;
typedef const __attribute__((address_space(1))) unsigned int glb_u32;

// async 16B/lane global->LDS DMA: lds dest = l + lane*16 (HW), src = g + lane*16
__device__ __forceinline__ void dma16(const half_t* g, half_t* l, int lane) {
  __builtin_amdgcn_global_load_lds((glb_u32*)(g + lane * 8), (lds_u32*)(l), 16, 0, 0);
}

// ============ prep: x (B,32,16) f32 -> xt (B,16,32) f16 (transpose f<->e) ============
__global__ __launch_bounds__(256) void prep_x(const float* __restrict__ x, half_t* __restrict__ xt) {
  __shared__ half_t t[8 * 512];
  const int tid = threadIdx.x;
  const size_t b0 = (size_t)blockIdx.x * 8;
#pragma unroll
  for (int i = 0; i < 4; ++i) {
    int idx = (i * 256 + tid) * 4;           // element index within 8 batch rows
    float4 v = *(const float4*)(x + b0 * 512 + idx);
    int e = idx & 15, f = (idx >> 4) & 31, b = idx >> 9;
    half_t* d = t + b * 512 + f;             // t layout [b][e*32+f]
    d[(e + 0) * 32] = (half_t)v.x;
    d[(e + 1) * 32] = (half_t)v.y;
    d[(e + 2) * 32] = (half_t)v.z;
    d[(e + 3) * 32] = (half_t)v.w;
  }
  __syncthreads();
#pragma unroll
  for (int i = 0; i < 2; ++i) {
    int c = i * 256 + tid;
    *(uint4*)(xt + b0 * 512 + c * 8) = *(const uint4*)(t + c * 8);
  }
}

// ===== prep: W (128,K) f32 -> f16 chunked [K/8][128][8]: chunk (k>>3)*128+o = W[o][k..k+8) =====
__global__ __launch_bounds__(256) void prep_w(const float* __restrict__ src, half_t* __restrict__ dst,
                                              int ktot, int nchunk) {
  int i = blockIdx.x * 256 + threadIdx.x;
  if (i >= nchunk) return;
  int o = i & 127, k8 = i >> 7;
  const float* s = src + (size_t)o * ktot + k8 * 8;
  float4 f0 = *(const float4*)s;
  float4 f1 = *(const float4*)(s + 4);
  union { half_t h[8]; uint4 u; } pk;
  pk.h[0] = (half_t)f0.x; pk.h[1] = (half_t)f0.y; pk.h[2] = (half_t)f0.z; pk.h[3] = (half_t)f0.w;
  pk.h[4] = (half_t)f1.x; pk.h[5] = (half_t)f1.y; pk.h[6] = (half_t)f1.z; pk.h[7] = (half_t)f1.w;
  *(uint4*)(dst + (size_t)i * 8) = pk.u;
}

// ============ one CIN layer: Y = relu(W @ Z + b), Z built on the fly ============
// Block: 256 thr, tile M=128(o) x N=128(8 batch x 16 e). Wave tile 64x64, mfma 16x16x32 f16.
// h fragments register-resident (kq fixed per lane). W staged via global_load_lds DMA,
// double-buffered 8KB/step, ONE __syncthreads per K-step (m97 structure).
template <int G, int KTOT, int KEEP, int OUT_BASE, bool H_OUT, bool H_IS_X>
__global__ __launch_bounds__(256, 2) void cin_layer(const half_t* __restrict__ xt,
                                                    const half_t* __restrict__ hin,
                                                    const half_t* __restrict__ wgt,
                                                    const float* __restrict__ bias,
                                                    half_t* __restrict__ hout,
                                                    float* __restrict__ out) {
  constexpr int NS = KTOT / 32;            // K-steps of 32
  constexpr int SPO = (G == 64) ? 16 : 8;  // steps per f-octet
  constexpr int NOCT = NS / SPO;           // 4 for both layer shapes
  constexpr int NSEL = (G == 64) ? 2 : 1;
  __shared__ __align__(16) half_t xt_lds[128 * XTP];
  __shared__ __align__(16) half_t w_lds[2 * 4096];   // double-buffered W step slabs (8KB each)
  __shared__ float bias_lds[128];

  const int tid = threadIdx.x;
  const int lane = tid & 63;
  const int wv = tid >> 6;
  const size_t b0 = (size_t)blockIdx.x * 8;

  // ---- stage xt: 128 rows (b,e) x 32 halves ----
  {
    const int r = tid >> 1, c = (tid & 1) * 16;
    const half_t* src = xt + b0 * 512 + r * 32 + c;
    uint4 q0 = *(const uint4*)(src);
    uint4 q1 = *(const uint4*)(src + 8);
    *(uint4*)(xt_lds + r * XTP + c) = q0;
    *(uint4*)(xt_lds + r * XTP + c + 8) = q1;
  }
  if (tid < 128) bias_lds[tid] = bias[tid];

  const int wm = (wv & 1) * 64;        // o offset of wave
  const int wb = (wv >> 1) * 4;        // batch offset of wave within block
  const int col = lane & 15;           // = e (A/B/C intra-tile index)
  const int kq = lane >> 4;            // k-quad (fixed per lane)

  int lrow[4];
#pragma unroll
  for (int ni = 0; ni < 4; ++ni) lrow[ni] = (wb + ni) * 16 + col;

  // ---- h fragments: register-resident for the whole K-loop ----
  v8h hreg[4][NSEL];
  if (!H_IS_X) {
#pragma unroll
    for (int ni = 0; ni < 4; ++ni) {
      const half_t* hp = hin + ((b0 + wb + ni) * 16 + col) * 64 + kq * 8;
      hreg[ni][0] = *(const v8h*)(hp);
      if (NSEL > 1) hreg[ni][NSEL - 1] = *(const v8h*)(hp + 32);
    }
  }

  // ---- DMA W step 0 into buf0 (2 rounds x 4 waves x 1KB = 8KB) ----
  dma16(wgt + wv * 512, w_lds + wv * 512, lane);
  dma16(wgt + 2048 + wv * 512, w_lds + 2048 + wv * 512, lane);

  __syncthreads();   // xt ready + DMA(0) drained (vmcnt(0) in barrier semantics)

  if (H_IS_X) {
#pragma unroll
    for (int ni = 0; ni < 4; ++ni)
      hreg[ni][0] = *(const v8h*)(xt_lds + lrow[ni] * XTP + kq * 8);
  }

  v4f acc[4][4] = {};

  for (int oct = 0; oct < NOCT; ++oct) {
    v8h xv[4];
#pragma unroll
    for (int ni = 0; ni < 4; ++ni)
      xv[ni] = *(const v8h*)(xt_lds + lrow[ni] * XTP + oct * 8);
#pragma unroll
    for (int t = 0; t < SPO; ++t) {
      const int s = oct * SPO + t;
      if (s != 0) __syncthreads();   // DMA(s) drained; all waves done reading buf[(s+1)&1]
      half_t* rb = w_lds + (s & 1) * 4096;
      if (s + 1 < NS) {              // DMA next step into the other buffer (overlaps compute)
        half_t* pb = w_lds + ((s + 1) & 1) * 4096;
        const half_t* wsrc = wgt + (size_t)(s + 1) * 4096;
        dma16(wsrc + wv * 512, pb + wv * 512, lane);
        dma16(wsrc + 2048 + wv * 512, pb + 2048 + wv * 512, lane);
      }
      const int j = (G == 64) ? (t >> 1) : t;     // f index within octet (static)
      const int sel = (G == 64) ? (t & 1) : 0;    // g-range select (static)
      v8h a[4], bfr[4];
#pragma unroll
      for (int mi = 0; mi < 4; ++mi)
        a[mi] = *(const v8h*)(rb + (kq * 128 + wm + mi * 16 + col) * 8);
#pragma unroll
      for (int ni = 0; ni < 4; ++ni)
        bfr[ni] = hreg[ni][sel] * xv[ni][j];      // Z fragment: x0[f,e]*h[g,e]
#pragma unroll
      for (int mi = 0; mi < 4; ++mi)
#pragma unroll
        for (int ni = 0; ni < 4; ++ni)
          acc[mi][ni] = __builtin_amdgcn_mfma_f32_16x16x32_f16(a[mi], bfr[ni], acc[mi][ni], 0, 0, 0);
    }
  }

  // ---- epilogue: bias + relu; rows>=64 -> h_next; rows<KEEP -> sum_e -> out ----
#pragma unroll
  for (int mi = 0; mi < 4; ++mi) {
    const int o_base = wm + mi * 16 + kq * 4;  // C rows o_base..o_base+3 for this lane
#pragma unroll
    for (int ni = 0; ni < 4; ++ni) {
      const int bb = wb + ni;
      float v[4];
#pragma unroll
      for (int r = 0; r < 4; ++r)
        v[r] = fmaxf(acc[mi][ni][r] + bias_lds[o_base + r], 0.0f);
      if (H_OUT && o_base >= 64) {   // wave-uniform: only wm=64 waves
        union { half_t h[4]; uint2 u; } pk;
#pragma unroll
        for (int r = 0; r < 4; ++r) pk.h[r] = (half_t)v[r];
        *(uint2*)(hout + ((b0 + bb) * 16 + col) * 64 + (o_base - 64)) = pk.u;
      }
      if (o_base < KEEP) {           // wave-uniform
#pragma unroll
        for (int r = 0; r < 4; ++r) {
          float sv = v[r];
          sv += __shfl_xor(sv, 1);
          sv += __shfl_xor(sv, 2);
          sv += __shfl_xor(sv, 4);
          sv += __shfl_xor(sv, 8);   // sum over e (16-lane group)
          if (col == 0) out[(b0 + bb) * 256 + OUT_BASE + o_base + r] = sv;
        }
      }
    }
  }
}

extern "C" void kernel_launch(void* const* d_in, const int* in_sizes, int n_in,
                              void* d_out, int out_size, void* d_ws, size_t ws_size,
                              hipStream_t stream) {
  const float* x  = (const float*)d_in[0];
  const float* W0 = (const float*)d_in[1];
  const float* b0 = (const float*)d_in[2];
  const float* W1 = (const float*)d_in[3];
  const float* b1 = (const float*)d_in[4];
  const float* W2 = (const float*)d_in[5];
  const float* b2 = (const float*)d_in[6];
  float* out = (float*)d_out;
  char* ws = (char*)d_ws;

  half_t* xt  = (half_t*)(ws);                          // 4 MB
  half_t* w0h = (half_t*)(ws + (4u << 20));             // 256 KB
  half_t* w1h = (half_t*)(ws + (4u << 20) + (256u << 10));   // 512 KB
  half_t* w2h = (half_t*)(ws + (4u << 20) + (768u << 10));   // 512 KB
  half_t* h1  = (half_t*)(ws + (4u << 20) + (1280u << 10));  // 8 MB
  half_t* h2  = (half_t*)(ws + (12u << 20) + (1280u << 10)); // 8 MB

  prep_x<<<512, 256, 0, stream>>>(x, xt);
  prep_w<<<64, 256, 0, stream>>>(W0, w0h, 1024, 16384);
  prep_w<<<128, 256, 0, stream>>>(W1, w1h, 2048, 32768);
  prep_w<<<128, 256, 0, stream>>>(W2, w2h, 2048, 32768);

  // layer 0: G=32 (h = x0), keep o<64 -> out ch [0,64), o>=64 -> h1
  cin_layer<32, 1024, 64, 0, true, true><<<512, 256, 0, stream>>>(xt, xt, w0h, b0, h1, out);
  // layer 1: G=64, keep o<64 -> out ch [64,128), o>=64 -> h2
  cin_layer<64, 2048, 64, 64, true, false><<<512, 256, 0, stream>>>(xt, h1, w1h, b1, h2, out);
  // layer 2: G=64, keep all 128 -> out ch [128,256)
  cin_layer<64, 2048, 128, 128, false, false><<<512, 256, 0, stream>>>(xt, h2, w2h, b2, nullptr, out);
}

// Round 4
// 182.376 us; speedup vs baseline: 1.2273x; 1.0303x over previous
//
#include <hip/hip_runtime.h>

typedef _Float16 half_t;
typedef _Float16 v8h __attribute__((ext_vector_type(8)));
typedef float v4f __attribute__((ext_vector_type(4)));

#define XTP 40   // xt LDS row pitch (halves): 32 data + 8 pad (16B-aligned rows)

typedef __attribute__((address_space(3))) unsigned int lds_u32;
typedef const __attribute__((address_space(1))) unsigned int glb_u32;

// async 16B/lane global->LDS DMA: lds dest = l + lane*16 (HW), src = g + lane*16
__device__ __forceinline__ void dma16(const half_t* g, half_t* l, int lane) {
  __builtin_amdgcn_global_load_lds((glb_u32*)(g + lane * 8), (lds_u32*)(l), 16, 0, 0);
}

// raw waitcnt: vmcnt(N), lgkmcnt/expcnt = no-wait  (gfx9 encoding)
#define WAITVM(N) __builtin_amdgcn_s_waitcnt(0xF70 | (N))
#define SCHED0()  __builtin_amdgcn_sched_barrier(0)

// ============ prep: x (B,32,16) f32 -> xt (B,16,32) f16 (transpose f<->e) ============
__global__ __launch_bounds__(256) void prep_x(const float* __restrict__ x, half_t* __restrict__ xt) {
  __shared__ half_t t[8 * 512];
  const int tid = threadIdx.x;
  const size_t b0 = (size_t)blockIdx.x * 8;
#pragma unroll
  for (int i = 0; i < 4; ++i) {
    int idx = (i * 256 + tid) * 4;           // element index within 8 batch rows
    float4 v = *(const float4*)(x + b0 * 512 + idx);
    int e = idx & 15, f = (idx >> 4) & 31, b = idx >> 9;
    half_t* d = t + b * 512 + f;             // t layout [b][e*32+f]
    d[(e + 0) * 32] = (half_t)v.x;
    d[(e + 1) * 32] = (half_t)v.y;
    d[(e + 2) * 32] = (half_t)v.z;
    d[(e + 3) * 32] = (half_t)v.w;
  }
  __syncthreads();
#pragma unroll
  for (int i = 0; i < 2; ++i) {
    int c = i * 256 + tid;
    *(uint4*)(xt + b0 * 512 + c * 8) = *(const uint4*)(t + c * 8);
  }
}

// ===== prep: W (128,K) f32 -> f16 chunked [K/8][128][8]: chunk (k>>3)*128+o = W[o][k..k+8) =====
__global__ __launch_bounds__(256) void prep_w(const float* __restrict__ src, half_t* __restrict__ dst,
                                              int ktot, int nchunk) {
  int i = blockIdx.x * 256 + threadIdx.x;
  if (i >= nchunk) return;
  int o = i & 127, k8 = i >> 7;
  const float* s = src + (size_t)o * ktot + k8 * 8;
  float4 f0 = *(const float4*)s;
  float4 f1 = *(const float4*)(s + 4);
  union { half_t h[8]; uint4 u; } pk;
  pk.h[0] = (half_t)f0.x; pk.h[1] = (half_t)f0.y; pk.h[2] = (half_t)f0.z; pk.h[3] = (half_t)f0.w;
  pk.h[4] = (half_t)f1.x; pk.h[5] = (half_t)f1.y; pk.h[6] = (half_t)f1.z; pk.h[7] = (half_t)f1.w;
  *(uint4*)(dst + (size_t)i * 8) = pk.u;
}

// ============ one CIN layer: Y = relu(W @ Z + b), Z built on the fly ============
// Block: 256 thr, tile M=128(o) x N=128(8 batch x 16 e). Wave tile 64x64, mfma 16x16x32 f16.
// h fragments register-resident (kq fixed per lane). W staged via global_load_lds DMA into a
// 4-slab ring, prefetch depth 3, raw s_waitcnt vmcnt(4)+s_barrier per step (no vmcnt(0) drain).
// Per-block K-octet rotation ((blockIdx>>3)&3) de-aliases L2 W reads across co-XCD blocks.
template <int G, int KTOT, int KEEP, int OUT_BASE, bool H_OUT, bool H_IS_X>
__global__ __launch_bounds__(256, 2) void cin_layer(const half_t* __restrict__ xt,
                                                    const half_t* __restrict__ hin,
                                                    const half_t* __restrict__ wgt,
                                                    const float* __restrict__ bias,
                                                    half_t* __restrict__ hout,
                                                    float* __restrict__ out) {
  constexpr int NS = KTOT / 32;            // K-steps of 32
  constexpr int SPO = (G == 64) ? 16 : 8;  // steps per f-octet
  constexpr int NOCT = NS / SPO;           // 4 for both layer shapes
  constexpr int NSEL = (G == 64) ? 2 : 1;
  __shared__ __align__(16) half_t xt_lds[128 * XTP];
  __shared__ __align__(16) half_t w_lds[4 * 4096];   // 4-slab W ring (8KB each)
  __shared__ float bias_lds[128];

  const int tid = threadIdx.x;
  const int lane = tid & 63;
  const int wv = tid >> 6;
  const size_t b0 = (size_t)blockIdx.x * 8;
  const int phase = (blockIdx.x >> 3) & 3;           // co-XCD blocks get different phases

  // ---- stage xt: 128 rows (b,e) x 32 halves ----
  {
    const int r = tid >> 1, c = (tid & 1) * 16;
    const half_t* src = xt + b0 * 512 + r * 32 + c;
    uint4 q0 = *(const uint4*)(src);
    uint4 q1 = *(const uint4*)(src + 8);
    *(uint4*)(xt_lds + r * XTP + c) = q0;
    *(uint4*)(xt_lds + r * XTP + c + 8) = q1;
  }
  if (tid < 128) bias_lds[tid] = bias[tid];

  const int wm = (wv & 1) * 64;        // o offset of wave
  const int wb = (wv >> 1) * 4;        // batch offset of wave within block
  const int col = lane & 15;           // = e (A/B/C intra-tile index)
  const int kq = lane >> 4;            // k-quad (fixed per lane)

  int lrow[4];
#pragma unroll
  for (int ni = 0; ni < 4; ++ni) lrow[ni] = (wb + ni) * 16 + col;

  // ---- h fragments: register-resident for the whole K-loop ----
  v8h hreg[4][NSEL];
  if (!H_IS_X) {
#pragma unroll
    for (int ni = 0; ni < 4; ++ni) {
      const half_t* hp = hin + ((b0 + wb + ni) * 16 + col) * 64 + kq * 8;
      hreg[ni][0] = *(const v8h*)(hp);
      if (NSEL > 1) hreg[ni][NSEL - 1] = *(const v8h*)(hp + 32);
    }
  }

  // ---- prologue: DMA pipeline slabs 0..2 (rotated) ----
#pragma unroll
  for (int p = 0; p < 3; ++p) {
    const half_t* wsrc = wgt + (size_t)(((phase)&3) * SPO + p) * 4096;  // p < SPO always
    half_t* pb = w_lds + (p & 3) * 4096;
    dma16(wsrc + wv * 512, pb + wv * 512, lane);
    dma16(wsrc + 2048 + wv * 512, pb + 2048 + wv * 512, lane);
  }

  __syncthreads();   // xt+bias visible; DMA 0..2 drained (one full drain, only here)

  if (H_IS_X) {
#pragma unroll
    for (int ni = 0; ni < 4; ++ni)
      hreg[ni][0] = *(const v8h*)(xt_lds + lrow[ni] * XTP + kq * 8);
  }

  v4f acc[4][4] = {};

  // ---- main octets (all but last), dynamic loop ----
#pragma unroll 1
  for (int oi = 0; oi < NOCT - 1; ++oi) {
    const int oct_a = (oi + phase) & 3;           // actual octet for compute
    const int next_a = (oi + 1 + phase) & 3;      // octet of cross-boundary prefetch
    v8h xv[4];
#pragma unroll
    for (int ni = 0; ni < 4; ++ni)
      xv[ni] = *(const v8h*)(xt_lds + lrow[ni] * XTP + oct_a * 8);
#pragma unroll
    for (int t = 0; t < SPO; ++t) {
      SCHED0(); WAITVM(4); __builtin_amdgcn_s_barrier(); SCHED0();
      {  // prefetch slab at pipeline distance +3
        const int tp = t + 3;
        const half_t* wsrc = (tp < SPO)
            ? wgt + (size_t)(oct_a * SPO + tp) * 4096
            : wgt + (size_t)(next_a * SPO + (tp - SPO)) * 4096;
        half_t* pb = w_lds + (tp & 3) * 4096;     // (oi*SPO + tp) & 3 == tp & 3 (SPO % 4 == 0)
        dma16(wsrc + wv * 512, pb + wv * 512, lane);
        dma16(wsrc + 2048 + wv * 512, pb + 2048 + wv * 512, lane);
      }
      const half_t* rb = w_lds + (t & 3) * 4096;
      const int j = (G == 64) ? (t >> 1) : t;
      const int sel = (G == 64) ? (t & 1) : 0;
      v8h a[4], bfr[4];
#pragma unroll
      for (int mi = 0; mi < 4; ++mi)
        a[mi] = *(const v8h*)(rb + (kq * 128 + wm + mi * 16 + col) * 8);
#pragma unroll
      for (int ni = 0; ni < 4; ++ni)
        bfr[ni] = hreg[ni][sel] * xv[ni][j];
#pragma unroll
      for (int mi = 0; mi < 4; ++mi)
#pragma unroll
        for (int ni = 0; ni < 4; ++ni)
          acc[mi][ni] = __builtin_amdgcn_mfma_f32_16x16x32_f16(a[mi], bfr[ni], acc[mi][ni], 0, 0, 0);
    }
  }

  // ---- final octet (peeled: pipeline tail waits) ----
  {
    const int oct_a = (NOCT - 1 + phase) & 3;
    v8h xv[4];
#pragma unroll
    for (int ni = 0; ni < 4; ++ni)
      xv[ni] = *(const v8h*)(xt_lds + lrow[ni] * XTP + oct_a * 8);
#pragma unroll
    for (int t = 0; t < SPO; ++t) {
      SCHED0();
      if (t < SPO - 2) { WAITVM(4); } else if (t == SPO - 2) { WAITVM(2); } else { WAITVM(0); }
      __builtin_amdgcn_s_barrier(); SCHED0();
      if (t + 3 < SPO) {
        const int tp = t + 3;
        const half_t* wsrc = wgt + (size_t)(oct_a * SPO + tp) * 4096;
        half_t* pb = w_lds + (tp & 3) * 4096;
        dma16(wsrc + wv * 512, pb + wv * 512, lane);
        dma16(wsrc + 2048 + wv * 512, pb + 2048 + wv * 512, lane);
      }
      const half_t* rb = w_lds + (t & 3) * 4096;
      const int j = (G == 64) ? (t >> 1) : t;
      const int sel = (G == 64) ? (t & 1) : 0;
      v8h a[4], bfr[4];
#pragma unroll
      for (int mi = 0; mi < 4; ++mi)
        a[mi] = *(const v8h*)(rb + (kq * 128 + wm + mi * 16 + col) * 8);
#pragma unroll
      for (int ni = 0; ni < 4; ++ni)
        bfr[ni] = hreg[ni][sel] * xv[ni][j];
#pragma unroll
      for (int mi = 0; mi < 4; ++mi)
#pragma unroll
        for (int ni = 0; ni < 4; ++ni)
          acc[mi][ni] = __builtin_amdgcn_mfma_f32_16x16x32_f16(a[mi], bfr[ni], acc[mi][ni], 0, 0, 0);
    }
  }

  // ---- epilogue: bias + relu; rows>=64 -> h_next; rows<KEEP -> sum_e -> out ----
#pragma unroll
  for (int mi = 0; mi < 4; ++mi) {
    const int o_base = wm + mi * 16 + kq * 4;  // C rows o_base..o_base+3 for this lane
#pragma unroll
    for (int ni = 0; ni < 4; ++ni) {
      const int bb = wb + ni;
      float v[4];
#pragma unroll
      for (int r = 0; r < 4; ++r)
        v[r] = fmaxf(acc[mi][ni][r] + bias_lds[o_base + r], 0.0f);
      if (H_OUT && o_base >= 64) {   // wave-uniform: only wm=64 waves
        union { half_t h[4]; uint2 u; } pk;
#pragma unroll
        for (int r = 0; r < 4; ++r) pk.h[r] = (half_t)v[r];
        *(uint2*)(hout + ((b0 + bb) * 16 + col) * 64 + (o_base - 64)) = pk.u;
      }
      if (o_base < KEEP) {           // wave-uniform
#pragma unroll
        for (int r = 0; r < 4; ++r) {
          float sv = v[r];
          sv += __shfl_xor(sv, 1);
          sv += __shfl_xor(sv, 2);
          sv += __shfl_xor(sv, 4);
          sv += __shfl_xor(sv, 8);   // sum over e (16-lane group)
          if (col == 0) out[(b0 + bb) * 256 + OUT_BASE + o_base + r] = sv;
        }
      }
    }
  }
}

extern "C" void kernel_launch(void* const* d_in, const int* in_sizes, int n_in,
                              void* d_out, int out_size, void* d_ws, size_t ws_size,
                              hipStream_t stream) {
  const float* x  = (const float*)d_in[0];
  const float* W0 = (const float*)d_in[1];
  const float* b0 = (const float*)d_in[2];
  const float* W1 = (const float*)d_in[3];
  const float* b1 = (const float*)d_in[4];
  const float* W2 = (const float*)d_in[5];
  const float* b2 = (const float*)d_in[6];
  float* out = (float*)d_out;
  char* ws = (char*)d_ws;

  half_t* xt  = (half_t*)(ws);                          // 4 MB
  half_t* w0h = (half_t*)(ws + (4u << 20));             // 256 KB
  half_t* w1h = (half_t*)(ws + (4u << 20) + (256u << 10));   // 512 KB
  half_t* w2h = (half_t*)(ws + (4u << 20) + (768u << 10));   // 512 KB
  half_t* h1  = (half_t*)(ws + (4u << 20) + (1280u << 10));  // 8 MB
  half_t* h2  = (half_t*)(ws + (12u << 20) + (1280u << 10)); // 8 MB

  prep_x<<<512, 256, 0, stream>>>(x, xt);
  prep_w<<<64, 256, 0, stream>>>(W0, w0h, 1024, 16384);
  prep_w<<<128, 256, 0, stream>>>(W1, w1h, 2048, 32768);
  prep_w<<<128, 256, 0, stream>>>(W2, w2h, 2048, 32768);

  // layer 0: G=32 (h = x0), keep o<64 -> out ch [0,64), o>=64 -> h1
  cin_layer<32, 1024, 64, 0, true, true><<<512, 256, 0, stream>>>(xt, xt, w0h, b0, h1, out);
  // layer 1: G=64, keep o<64 -> out ch [64,128), o>=64 -> h2
  cin_layer<64, 2048, 64, 64, true, false><<<512, 256, 0, stream>>>(xt, h1, w1h, b1, h2, out);
  // layer 2: G=64, keep all 128 -> out ch [128,256)
  cin_layer<64, 2048, 128, 128, false, false><<<512, 256, 0, stream>>>(xt, h2, w2h, b2, nullptr, out);
}

// Round 5
// 177.356 us; speedup vs baseline: 1.2621x; 1.0283x over previous
//
#include <hip/hip_runtime.h>

typedef _Float16 half_t;
typedef _Float16 v8h __attribute__((ext_vector_type(8)));
typedef float v4f __attribute__((ext_vector_type(4)));

#define XTP 40   // xt LDS row pitch (halves): 32 data + 8 pad (16B-aligned rows)

// ============ prep: x (B,32,16) f32 -> xt (B,16,32) f16 (transpose f<->e) ============
__global__ __launch_bounds__(256) void prep_x(const float* __restrict__ x, half_t* __restrict__ xt) {
  __shared__ half_t t[8 * 512];
  const int tid = threadIdx.x;
  const size_t b0 = (size_t)blockIdx.x * 8;
#pragma unroll
  for (int i = 0; i < 4; ++i) {
    int idx = (i * 256 + tid) * 4;           // element index within 8 batch rows
    float4 v = *(const float4*)(x + b0 * 512 + idx);
    int e = idx & 15, f = (idx >> 4) & 31, b = idx >> 9;
    half_t* d = t + b * 512 + f;             // t layout [b][e*32+f]
    d[(e + 0) * 32] = (half_t)v.x;
    d[(e + 1) * 32] = (half_t)v.y;
    d[(e + 2) * 32] = (half_t)v.z;
    d[(e + 3) * 32] = (half_t)v.w;
  }
  __syncthreads();
#pragma unroll
  for (int i = 0; i < 2; ++i) {
    int c = i * 256 + tid;
    *(uint4*)(xt + b0 * 512 + c * 8) = *(const uint4*)(t + c * 8);
  }
}

// ===== prep: W (128,K) f32 -> f16 chunked [K/8][128][8]: chunk (k>>3)*128+o = W[o][k..k+8) =====
__global__ __launch_bounds__(256) void prep_w(const float* __restrict__ src, half_t* __restrict__ dst,
                                              int ktot, int nchunk) {
  int i = blockIdx.x * 256 + threadIdx.x;
  if (i >= nchunk) return;
  int o = i & 127, k8 = i >> 7;
  const float* s = src + (size_t)o * ktot + k8 * 8;
  float4 f0 = *(const float4*)s;
  float4 f1 = *(const float4*)(s + 4);
  union { half_t h[8]; uint4 u; } pk;
  pk.h[0] = (half_t)f0.x; pk.h[1] = (half_t)f0.y; pk.h[2] = (half_t)f0.z; pk.h[3] = (half_t)f0.w;
  pk.h[4] = (half_t)f1.x; pk.h[5] = (half_t)f1.y; pk.h[6] = (half_t)f1.z; pk.h[7] = (half_t)f1.w;
  *(uint4*)(dst + (size_t)i * 8) = pk.u;
}

// ============ one CIN layer: Y = relu(W @ Z + b), Z built on the fly ============
// Block: 256 thr, tile M=128(o) x N=128(8 batch x 16 e). Wave tile 64x64, mfma 16x16x32 f16.
// h fragments register-resident (kq fixed per lane). W streamed global->register ring aw[4][4],
// prefetch depth 3 (slot = linear_step & 3, SPO % 4 == 0). NO barriers, NO LDS in the K-loop:
// waves free-run so the 2 waves/SIMD anti-phase and fill each other's MFMA-pipe gaps.
// Per-block K-octet rotation ((blockIdx>>3)&3) de-aliases L2 W reads across co-XCD blocks.
template <int G, int KTOT, int KEEP, int OUT_BASE, bool H_OUT, bool H_IS_X>
__global__ __launch_bounds__(256, 2) void cin_layer(const half_t* __restrict__ xt,
                                                    const half_t* __restrict__ hin,
                                                    const half_t* __restrict__ wgt,
                                                    const float* __restrict__ bias,
                                                    half_t* __restrict__ hout,
                                                    float* __restrict__ out) {
  constexpr int NS = KTOT / 32;            // K-steps of 32
  constexpr int SPO = (G == 64) ? 16 : 8;  // steps per f-octet (SPO % 4 == 0)
  constexpr int NOCT = NS / SPO;           // 4 for both layer shapes
  constexpr int NSEL = (G == 64) ? 2 : 1;
  __shared__ __align__(16) half_t xt_lds[128 * XTP];
  __shared__ float bias_lds[128];

  const int tid = threadIdx.x;
  const int lane = tid & 63;
  const int wv = tid >> 6;
  const size_t b0 = (size_t)blockIdx.x * 8;
  const int phase = (blockIdx.x >> 3) & 3;           // co-XCD blocks start on different octets

  // ---- stage xt: 128 rows (b,e) x 32 halves ----
  {
    const int r = tid >> 1, c = (tid & 1) * 16;
    const half_t* src = xt + b0 * 512 + r * 32 + c;
    uint4 q0 = *(const uint4*)(src);
    uint4 q1 = *(const uint4*)(src + 8);
    *(uint4*)(xt_lds + r * XTP + c) = q0;
    *(uint4*)(xt_lds + r * XTP + c + 8) = q1;
  }
  if (tid < 128) bias_lds[tid] = bias[tid];

  const int wm = (wv & 1) * 64;        // o offset of wave
  const int wb = (wv >> 1) * 4;        // batch offset of wave within block
  const int col = lane & 15;           // = e (A/B/C intra-tile index)
  const int kq = lane >> 4;            // k-quad (fixed per lane)

  int lrow[4];
#pragma unroll
  for (int ni = 0; ni < 4; ++ni) lrow[ni] = (wb + ni) * 16 + col;

  // ---- h fragments: register-resident for the whole K-loop ----
  v8h hreg[4][NSEL];
  if (!H_IS_X) {
#pragma unroll
    for (int ni = 0; ni < 4; ++ni) {
      const half_t* hp = hin + ((b0 + wb + ni) * 16 + col) * 64 + kq * 8;
      hreg[ni][0] = *(const v8h*)(hp);
      if (NSEL > 1) hreg[ni][NSEL - 1] = *(const v8h*)(hp + 32);
    }
  }

  __syncthreads();   // xt/bias visible; drains ALL prior VMEM -> clean vmcnt baseline for W ring

  if (H_IS_X) {
#pragma unroll
    for (int ni = 0; ni < 4; ++ni)
      hreg[ni][0] = *(const v8h*)(xt_lds + lrow[ni] * XTP + kq * 8);
  }

  // ---- W register ring: lane's chunk (kq*128 + wm + col), group stride 512 chunks ----
  const v8h* wb_ = (const v8h*)wgt + (kq * 128 + wm + col);
  v8h aw[4][4];
  // prologue: groups for linear steps 0,1,2 (octet `phase`) -> slots 0,1,2
#pragma unroll
  for (int p = 0; p < 3; ++p) {
    const v8h* src = wb_ + (size_t)(phase * SPO + p) * 512;
#pragma unroll
    for (int mi = 0; mi < 4; ++mi) aw[p][mi] = src[mi * 16];
  }

  v4f acc[4][4] = {};

#pragma unroll 1
  for (int oi = 0; oi < NOCT; ++oi) {
    const int oct_a = (oi + phase) & 3;              // octet being computed
    v8h xv[4];
#pragma unroll
    for (int ni = 0; ni < 4; ++ni)
      xv[ni] = *(const v8h*)(xt_lds + lrow[ni] * XTP + oct_a * 8);
#pragma unroll
    for (int t = 0; t < SPO; ++t) {
      // prefetch linear step s+3 into slot (t+3)&3 (wraps into octet `phase` at the very
      // end: harmless in-bounds re-read, never consumed)
      {
        const int tp = (t + 3) % SPO;                       // static
        const int oct_p = (oi + ((t + 3) >= SPO ? 1 : 0) + phase) & 3;
        const v8h* src = wb_ + (size_t)(oct_p * SPO + tp) * 512;
#pragma unroll
        for (int mi = 0; mi < 4; ++mi) aw[(t + 3) & 3][mi] = src[mi * 16];
      }
      const int j = (G == 64) ? (t >> 1) : t;     // f index within octet (static)
      const int sel = (G == 64) ? (t & 1) : 0;    // g-range select (static)
      v8h bfr[4];
#pragma unroll
      for (int ni = 0; ni < 4; ++ni)
        bfr[ni] = hreg[ni][sel] * xv[ni][j];      // Z fragment: x0[f,e]*h[g,e]
#pragma unroll
      for (int mi = 0; mi < 4; ++mi) {
        v8h a = aw[t & 3][mi];
#pragma unroll
        for (int ni = 0; ni < 4; ++ni)
          acc[mi][ni] = __builtin_amdgcn_mfma_f32_16x16x32_f16(a, bfr[ni], acc[mi][ni], 0, 0, 0);
      }
    }
  }

  // ---- epilogue: bias + relu; rows>=64 -> h_next; rows<KEEP -> sum_e -> out ----
#pragma unroll
  for (int mi = 0; mi < 4; ++mi) {
    const int o_base = wm + mi * 16 + kq * 4;  // C rows o_base..o_base+3 for this lane
#pragma unroll
    for (int ni = 0; ni < 4; ++ni) {
      const int bb = wb + ni;
      float v[4];
#pragma unroll
      for (int r = 0; r < 4; ++r)
        v[r] = fmaxf(acc[mi][ni][r] + bias_lds[o_base + r], 0.0f);
      if (H_OUT && o_base >= 64) {   // wave-uniform: only wm=64 waves
        union { half_t h[4]; uint2 u; } pk;
#pragma unroll
        for (int r = 0; r < 4; ++r) pk.h[r] = (half_t)v[r];
        *(uint2*)(hout + ((b0 + bb) * 16 + col) * 64 + (o_base - 64)) = pk.u;
      }
      if (o_base < KEEP) {           // wave-uniform
#pragma unroll
        for (int r = 0; r < 4; ++r) {
          float sv = v[r];
          sv += __shfl_xor(sv, 1);
          sv += __shfl_xor(sv, 2);
          sv += __shfl_xor(sv, 4);
          sv += __shfl_xor(sv, 8);   // sum over e (16-lane group)
          if (col == 0) out[(b0 + bb) * 256 + OUT_BASE + o_base + r] = sv;
        }
      }
    }
  }
}

extern "C" void kernel_launch(void* const* d_in, const int* in_sizes, int n_in,
                              void* d_out, int out_size, void* d_ws, size_t ws_size,
                              hipStream_t stream) {
  const float* x  = (const float*)d_in[0];
  const float* W0 = (const float*)d_in[1];
  const float* b0 = (const float*)d_in[2];
  const float* W1 = (const float*)d_in[3];
  const float* b1 = (const float*)d_in[4];
  const float* W2 = (const float*)d_in[5];
  const float* b2 = (const float*)d_in[6];
  float* out = (float*)d_out;
  char* ws = (char*)d_ws;

  half_t* xt  = (half_t*)(ws);                          // 4 MB
  half_t* w0h = (half_t*)(ws + (4u << 20));             // 256 KB
  half_t* w1h = (half_t*)(ws + (4u << 20) + (256u << 10));   // 512 KB
  half_t* w2h = (half_t*)(ws + (4u << 20) + (768u << 10));   // 512 KB
  half_t* h1  = (half_t*)(ws + (4u << 20) + (1280u << 10));  // 8 MB
  half_t* h2  = (half_t*)(ws + (12u << 20) + (1280u << 10)); // 8 MB

  prep_x<<<512, 256, 0, stream>>>(x, xt);
  prep_w<<<64, 256, 0, stream>>>(W0, w0h, 1024, 16384);
  prep_w<<<128, 256, 0, stream>>>(W1, w1h, 2048, 32768);
  prep_w<<<128, 256, 0, stream>>>(W2, w2h, 2048, 32768);

  // layer 0: G=32 (h = x0), keep o<64 -> out ch [0,64), o>=64 -> h1
  cin_layer<32, 1024, 64, 0, true, true><<<512, 256, 0, stream>>>(xt, xt, w0h, b0, h1, out);
  // layer 1: G=64, keep o<64 -> out ch [64,128), o>=64 -> h2
  cin_layer<64, 2048, 64, 64, true, false><<<512, 256, 0, stream>>>(xt, h1, w1h, b1, h2, out);
  // layer 2: G=64, keep all 128 -> out ch [128,256)
  cin_layer<64, 2048, 128, 128, false, false><<<512, 256, 0, stream>>>(xt, h2, w2h, b2, nullptr, out);
}